// Round 1
// baseline (281.251 us; speedup 1.0000x reference)
//
#include <hip/hip_runtime.h>

// Weighted keypoint MSE loss:
//   oob = (tx<0)|(tx>1024)|(ty<0)|(ty>1024)
//   loss = sum( (oob ? 0.01 : 1.0) * ((ox-tx)^2 + (oy-ty)^2) ) / B
// Inputs: output [B,K,2] fp32, target [B,K,2] fp32, B=4096, K=4096.
// Memory-bound: 268 MB read -> ~43 us floor at 6.3 TB/s.

#define WIDTH_F  1024.0f
#define HEIGHT_F 1024.0f
#define OOB_W    0.01f

__global__ __launch_bounds__(256) void res_kp_loss_kernel(
    const float4* __restrict__ out4,
    const float4* __restrict__ tgt4,
    float* __restrict__ result,
    int n4,            // number of float4 elements (= 2 keypoints each)
    float inv_b) {
    float acc = 0.0f;
    int idx    = blockIdx.x * blockDim.x + threadIdx.x;
    int stride = gridDim.x * blockDim.x;

    for (int i = idx; i < n4; i += stride) {
        float4 o = out4[i];
        float4 t = tgt4[i];

        // keypoint A: (o.x,o.y) vs (t.x,t.y)
        float dx = o.x - t.x;
        float dy = o.y - t.y;
        float sq = dx * dx + dy * dy;
        bool oob = (t.x < 0.0f) || (t.x > WIDTH_F) || (t.y < 0.0f) || (t.y > HEIGHT_F);
        acc += (oob ? OOB_W : 1.0f) * sq;

        // keypoint B: (o.z,o.w) vs (t.z,t.w)
        dx = o.z - t.z;
        dy = o.w - t.w;
        sq = dx * dx + dy * dy;
        oob = (t.z < 0.0f) || (t.z > WIDTH_F) || (t.w < 0.0f) || (t.w > HEIGHT_F);
        acc += (oob ? OOB_W : 1.0f) * sq;
    }

    // wave-64 shuffle reduction
    #pragma unroll
    for (int off = 32; off > 0; off >>= 1)
        acc += __shfl_down(acc, off, 64);

    __shared__ float wave_sums[4];
    int lane = threadIdx.x & 63;
    int wave = threadIdx.x >> 6;
    if (lane == 0) wave_sums[wave] = acc;
    __syncthreads();

    if (threadIdx.x == 0) {
        float s = (wave_sums[0] + wave_sums[1]) + (wave_sums[2] + wave_sums[3]);
        atomicAdd(result, s * inv_b);  // device-scope by default on CDNA
    }
}

extern "C" void kernel_launch(void* const* d_in, const int* in_sizes, int n_in,
                              void* d_out, int out_size, void* d_ws, size_t ws_size,
                              hipStream_t stream) {
    const float4* out4 = (const float4*)d_in[0];  // output [B,K,2] fp32
    const float4* tgt4 = (const float4*)d_in[1];  // target [B,K,2] fp32
    float* result = (float*)d_out;

    const int total_floats = in_sizes[0];          // B*K*2 = 33,554,432
    const int n4 = total_floats / 4;               // 8,388,608 float4 loads per array
    const float inv_b = 1.0f / 4096.0f;            // B = 4096

    // d_out is poisoned 0xAA before every timed launch — zero it (async, capture-safe)
    hipMemsetAsync(d_out, 0, out_size * sizeof(float), stream);

    const int block = 256;
    const int grid = 2048;  // 8 blocks/CU on 256 CUs; grid-stride covers the rest
    res_kp_loss_kernel<<<grid, block, 0, stream>>>(out4, tgt4, result, n4, inv_b);
}

// Round 2
// 279.995 us; speedup vs baseline: 1.0045x; 1.0045x over previous
//
#include <hip/hip_runtime.h>

// Weighted keypoint MSE loss:
//   oob = (tx<0)|(tx>1024)|(ty<0)|(ty>1024)
//   loss = sum( (oob ? 0.01 : 1.0) * ((ox-tx)^2 + (oy-ty)^2) ) / B
// Inputs: output [B,K,2] fp32, target [B,K,2] fp32, B=4096, K=4096.
// 268 MB read total -> ~43 us floor at 6.3 TB/s HBM (less if L3-resident).
//
// R1 lesson: compiler kept VGPR=12 and did NOT unroll the grid-stride loop
// -> only 2 loads in flight per wave -> latency-bound at 2.5 TB/s.
// R2: manual unroll x4, all 8 loads issued before any use.

#define WIDTH_F  1024.0f
#define HEIGHT_F 1024.0f
#define OOB_W    0.01f

__device__ __forceinline__ float kp_pair(float4 o, float4 t) {
    float dx = o.x - t.x;
    float dy = o.y - t.y;
    float sqA = dx * dx + dy * dy;
    bool oobA = (t.x < 0.0f) || (t.x > WIDTH_F) || (t.y < 0.0f) || (t.y > HEIGHT_F);
    float dz = o.z - t.z;
    float dw = o.w - t.w;
    float sqB = dz * dz + dw * dw;
    bool oobB = (t.z < 0.0f) || (t.z > WIDTH_F) || (t.w < 0.0f) || (t.w > HEIGHT_F);
    return (oobA ? OOB_W : 1.0f) * sqA + (oobB ? OOB_W : 1.0f) * sqB;
}

__global__ __launch_bounds__(256) void res_kp_loss_kernel(
    const float4* __restrict__ out4,
    const float4* __restrict__ tgt4,
    float* __restrict__ result,
    int n4,
    float inv_b) {
    int idx    = blockIdx.x * blockDim.x + threadIdx.x;
    int stride = gridDim.x * blockDim.x;

    float acc0 = 0.0f, acc1 = 0.0f, acc2 = 0.0f, acc3 = 0.0f;

    int i = idx;
    // unrolled-by-4 main loop: 8 independent global_load_dwordx4 in flight
    for (; i + 3 * stride < n4; i += 4 * stride) {
        float4 o0 = out4[i];
        float4 o1 = out4[i + stride];
        float4 o2 = out4[i + 2 * stride];
        float4 o3 = out4[i + 3 * stride];
        float4 t0 = tgt4[i];
        float4 t1 = tgt4[i + stride];
        float4 t2 = tgt4[i + 2 * stride];
        float4 t3 = tgt4[i + 3 * stride];
        acc0 += kp_pair(o0, t0);
        acc1 += kp_pair(o1, t1);
        acc2 += kp_pair(o2, t2);
        acc3 += kp_pair(o3, t3);
    }
    // tail (empty for the bench shape: 16 iters % 4 == 0)
    for (; i < n4; i += stride) {
        acc0 += kp_pair(out4[i], tgt4[i]);
    }

    float acc = (acc0 + acc1) + (acc2 + acc3);

    // wave-64 shuffle reduction
    #pragma unroll
    for (int off = 32; off > 0; off >>= 1)
        acc += __shfl_down(acc, off, 64);

    __shared__ float wave_sums[4];
    int lane = threadIdx.x & 63;
    int wave = threadIdx.x >> 6;
    if (lane == 0) wave_sums[wave] = acc;
    __syncthreads();

    if (threadIdx.x == 0) {
        float s = (wave_sums[0] + wave_sums[1]) + (wave_sums[2] + wave_sums[3]);
        atomicAdd(result, s * inv_b);  // device-scope by default on CDNA
    }
}

extern "C" void kernel_launch(void* const* d_in, const int* in_sizes, int n_in,
                              void* d_out, int out_size, void* d_ws, size_t ws_size,
                              hipStream_t stream) {
    const float4* out4 = (const float4*)d_in[0];  // output [B,K,2] fp32
    const float4* tgt4 = (const float4*)d_in[1];  // target [B,K,2] fp32
    float* result = (float*)d_out;

    const int total_floats = in_sizes[0];          // B*K*2 = 33,554,432
    const int n4 = total_floats / 4;               // 8,388,608 float4 per array
    const float inv_b = 1.0f / 4096.0f;            // B = 4096

    // d_out is poisoned 0xAA before every timed launch — zero it (async, capture-safe)
    hipMemsetAsync(d_out, 0, out_size * sizeof(float), stream);

    const int block = 256;
    const int grid = 2048;  // 2048*256 threads = 8192 waves = 32 waves/CU (max residency)
    res_kp_loss_kernel<<<grid, block, 0, stream>>>(out4, tgt4, result, n4, inv_b);
}

// Round 3
// 275.827 us; speedup vs baseline: 1.0197x; 1.0151x over previous
//
#include <hip/hip_runtime.h>

// Weighted keypoint MSE loss:
//   oob = (tx<0)|(tx>1024)|(ty<0)|(ty>1024)
//   loss = sum( (oob ? 0.01 : 1.0) * ((ox-tx)^2 + (oy-ty)^2) ) / B
// Inputs: output [B,K,2] fp32, target [B,K,2] fp32, B=4096, K=4096. 268 MB read.
//
// R1: VGPR=12, 2 loads in flight -> 104 us, latency-bound (2.58 TB/s).
// R2: unroll x4 but compiler re-serialized (VGPR=28 proves it) -> unchanged.
// R3: unroll x8 + asm memory clobber between load block and use block so all
//     16 global_load_dwordx4 issue before the first s_waitcnt.

#define WIDTH_F  1024.0f
#define HEIGHT_F 1024.0f
#define OOB_W    0.01f
#define UNROLL   8

__device__ __forceinline__ float kp_pair(float4 o, float4 t) {
    float dx = o.x - t.x;
    float dy = o.y - t.y;
    float sqA = dx * dx + dy * dy;
    bool oobA = (t.x < 0.0f) || (t.x > WIDTH_F) || (t.y < 0.0f) || (t.y > HEIGHT_F);
    float dz = o.z - t.z;
    float dw = o.w - t.w;
    float sqB = dz * dz + dw * dw;
    bool oobB = (t.z < 0.0f) || (t.z > WIDTH_F) || (t.w < 0.0f) || (t.w > HEIGHT_F);
    return (oobA ? OOB_W : 1.0f) * sqA + (oobB ? OOB_W : 1.0f) * sqB;
}

__global__ __launch_bounds__(256) void res_kp_loss_kernel(
    const float4* __restrict__ out4,
    const float4* __restrict__ tgt4,
    float* __restrict__ result,
    int n4,
    float inv_b) {
    int idx    = blockIdx.x * blockDim.x + threadIdx.x;
    int stride = gridDim.x * blockDim.x;

    float acc[UNROLL];
    #pragma unroll
    for (int u = 0; u < UNROLL; ++u) acc[u] = 0.0f;

    int i = idx;
    for (; i + (UNROLL - 1) * stride < n4; i += UNROLL * stride) {
        float4 o[UNROLL], t[UNROLL];
        #pragma unroll
        for (int u = 0; u < UNROLL; ++u) o[u] = out4[i + u * stride];
        #pragma unroll
        for (int u = 0; u < UNROLL; ++u) t[u] = tgt4[i + u * stride];
        // Scheduling fence: loads above may not sink below this point, so all
        // 16 global_load_dwordx4 are issued before the first consuming waitcnt.
        asm volatile("" ::: "memory");
        #pragma unroll
        for (int u = 0; u < UNROLL; ++u) acc[u] += kp_pair(o[u], t[u]);
    }
    // tail (empty for the bench shape: 16 iters per thread, 16 % 8 == 0)
    for (; i < n4; i += stride) acc[0] += kp_pair(out4[i], tgt4[i]);

    float a0 = (acc[0] + acc[1]) + (acc[2] + acc[3]);
    float a1 = (acc[4] + acc[5]) + (acc[6] + acc[7]);
    float accs = a0 + a1;

    // wave-64 shuffle reduction
    #pragma unroll
    for (int off = 32; off > 0; off >>= 1)
        accs += __shfl_down(accs, off, 64);

    __shared__ float wave_sums[4];
    int lane = threadIdx.x & 63;
    int wave = threadIdx.x >> 6;
    if (lane == 0) wave_sums[wave] = accs;
    __syncthreads();

    if (threadIdx.x == 0) {
        float s = (wave_sums[0] + wave_sums[1]) + (wave_sums[2] + wave_sums[3]);
        atomicAdd(result, s * inv_b);  // device-scope by default on CDNA
    }
}

extern "C" void kernel_launch(void* const* d_in, const int* in_sizes, int n_in,
                              void* d_out, int out_size, void* d_ws, size_t ws_size,
                              hipStream_t stream) {
    const float4* out4 = (const float4*)d_in[0];  // output [B,K,2] fp32
    const float4* tgt4 = (const float4*)d_in[1];  // target [B,K,2] fp32
    float* result = (float*)d_out;

    const int total_floats = in_sizes[0];          // B*K*2 = 33,554,432
    const int n4 = total_floats / 4;               // 8,388,608 float4 per array
    const float inv_b = 1.0f / 4096.0f;            // B = 4096

    // d_out is poisoned 0xAA before every timed launch — zero it (async, capture-safe)
    hipMemsetAsync(d_out, 0, out_size * sizeof(float), stream);

    const int block = 256;
    const int grid = 2048;  // 16 float4 per thread per array; 8192 waves total
    res_kp_loss_kernel<<<grid, block, 0, stream>>>(out4, tgt4, result, n4, inv_b);
}